// Round 2
// baseline (214.534 us; speedup 1.0000x reference)
//
#include <hip/hip_runtime.h>
#include <hip/hip_cooperative_groups.h>
#include <math.h>

// Problem constants (from reference)
#define INPUT_DIM 30000
#define UNITS     2048
#define NNZ       500000
#define BATCH     32

namespace cg = cooperative_groups;

// ---------------------------------------------------------------------------
// R6: single cooperative kernel. Rationale: per-kernel micro-scheduling is
// exhausted (R5: 16-in-flight gather restructure was perf-neutral). Total
// unique traffic ~22 MB (~5-8 us at BW) vs ~40 us observed for the 3-kernel
// chain -> the cost is serial structure: 3 launches, transpose->scatter and
// scatter->final dependencies, and a cold-miss latency ramp at each kernel
// head. Fusing with grid.sync() lets the 8 MB cold idx load (phase A) fly
// under the transpose (phase B), and the final tanh read ws2/spill L2-hot.
// Grid 512x512 = exactly co-resident (2 WG/CU, 16 waves/CU); launch_bounds
// (512,4) caps VGPR at 128 to guarantee cooperative residency.
// ---------------------------------------------------------------------------
__global__ __launch_bounds__(512, 4) void fused_k(const float* __restrict__ x,
                                                  const float* __restrict__ kv,
                                                  const float* __restrict__ bias,
                                                  const int*   __restrict__ idx,
                                                  float* __restrict__ out,
                                                  float* __restrict__ xt,
                                                  float* __restrict__ ws2,
                                                  float* __restrict__ spill) {
    __shared__ float tile[32][65];                // transpose staging (+1 pad)
    __shared__ float part[32 * 128];              // [es][b 0..31][rl 0..3]
    __shared__ int   colA[4];

    const int t    = threadIdx.x;
    const int rl   = t & 3;
    const int bg   = (t >> 2) & 3;
    const int es   = t >> 4;                      // 0..31
    const int r    = blockIdx.x * 4 + rl;         // residue 0..2047
    const int boff = bg * 8;

    // int64 vs int32 index detection (uniform): int64 LE -> high words zero.
    const bool is64 = ((idx[3] | idx[5] | idx[7]) == 0);
    const int  col0 = is64 ? idx[4 * r + 2] : idx[2 * r + 1];

    // ---- phase A: issue ALL idx/kv loads now; latency hides under phase B --
    const int base = r + UNITS * es;              // 0..65535
    int   rows[8], cols[8];
    float vals[8];
    if (is64) {
        const int4* __restrict__ p = (const int4*)idx;
        #pragma unroll
        for (int j = 0; j < 8; ++j) {
            int  e  = base + j * 65536;           // entry stripe
            bool ok = e < NNZ;
            int4 q  = ok ? p[e] : make_int4(0, 0, col0, 0);
            rows[j] = q.x; cols[j] = q.z;
            vals[j] = ok ? kv[e] : 0.f;
        }
    } else {
        const int2* __restrict__ p = (const int2*)idx;
        #pragma unroll
        for (int j = 0; j < 8; ++j) {
            int  e  = base + j * 65536;
            bool ok = e < NNZ;
            int2 q  = ok ? p[e] : make_int2(0, col0);
            rows[j] = q.x; cols[j] = q.y;
            vals[j] = ok ? kv[e] : 0.f;
        }
    }

    // ---- zero ws2 + spill (contiguous, 32768 float4) ----
    {
        int gid = blockIdx.x * 512 + t;
        if (gid < 32768) ((float4*)ws2)[gid] = make_float4(0.f, 0.f, 0.f, 0.f);
    }

    // ---- phase B: transpose x [32][30000] -> xt [30000][32] ----
    if (blockIdx.x < (INPUT_DIM + 63) / 64) {     // 469 active WGs
        const int i0  = blockIdx.x * 64;
        const int w   = t >> 6;                   // wave 0..7
        const int l   = t & 63;
        const bool iok = (i0 + l) < INPUT_DIM;
        #pragma unroll
        for (int bb = 0; bb < 4; ++bb) {          // 4 batch rows per wave
            int b = w * 4 + bb;
            tile[b][l] = iok ? x[b * INPUT_DIM + i0 + l] : 0.f;
        }
        __syncthreads();
        const int il = t >> 3;                    // 0..63
        const int b4 = t & 7;                     // batch quad
        if (i0 + il < INPUT_DIM)
            ((float4*)xt)[(size_t)(i0 + il) * 8 + b4] =
                make_float4(tile[b4 * 4 + 0][il], tile[b4 * 4 + 1][il],
                            tile[b4 * 4 + 2][il], tile[b4 * 4 + 3][il]);
    }

    cg::this_grid().sync();

    // ---- phase C: gathers (rows already in registers) + accumulate ----
    float4 g0[8], g1[8];
    #pragma unroll
    for (int j = 0; j < 8; ++j) {
        const float4* __restrict__ xr = (const float4*)(xt + rows[j] * 32 + boff);
        g0[j] = xr[0];
        g1[j] = xr[1];
    }
    __builtin_amdgcn_sched_barrier(0);            // keep gathers issued first

    float acc[8];
    #pragma unroll
    for (int k = 0; k < 8; ++k) acc[k] = 0.f;

    #pragma unroll
    for (int j = 0; j < 8; ++j) {
        float v = vals[j];
        if (cols[j] == col0) {                    // uniformly true for this data
            acc[0] += v * g0[j].x; acc[1] += v * g0[j].y;
            acc[2] += v * g0[j].z; acc[3] += v * g0[j].w;
            acc[4] += v * g1[j].x; acc[5] += v * g1[j].y;
            acc[6] += v * g1[j].z; acc[7] += v * g1[j].w;
        } else {                                  // correctness fallback
            float* __restrict__ sp = spill + cols[j];
            atomicAdd(sp + (boff + 0) * UNITS, v * g0[j].x);
            atomicAdd(sp + (boff + 1) * UNITS, v * g0[j].y);
            atomicAdd(sp + (boff + 2) * UNITS, v * g0[j].z);
            atomicAdd(sp + (boff + 3) * UNITS, v * g0[j].w);
            atomicAdd(sp + (boff + 4) * UNITS, v * g1[j].x);
            atomicAdd(sp + (boff + 5) * UNITS, v * g1[j].y);
            atomicAdd(sp + (boff + 6) * UNITS, v * g1[j].z);
            atomicAdd(sp + (boff + 7) * UNITS, v * g1[j].w);
        }
    }

    // combine 32 es-stripes via LDS (bank-aliasing 2-way on reduce: free)
    #pragma unroll
    for (int bb = 0; bb < 8; ++bb)
        part[es * 128 + (boff + bb) * 4 + rl] = acc[bb];
    if (t < 4) colA[t] = col0;
    __syncthreads();

    if (t < 128) {
        const int rr = t & 3;
        const int b  = t >> 2;                    // 0..31
        float s = 0.f;
        #pragma unroll
        for (int e = 0; e < 32; ++e) s += part[e * 128 + b * 4 + rr];
        // atomic: distinct addrs when cols bijective; correct if not
        atomicAdd(&ws2[b * UNITS + colA[rr]], s);
    }

    cg::this_grid().sync();

    // ---- phase D: out = tanh(ws2 + spill + bias), L2-hot operands ----
    {
        int gid = blockIdx.x * 512 + t;
        if (gid < BATCH * UNITS) {
            int c = gid & (UNITS - 1);
            out[gid] = tanhf(ws2[gid] + spill[gid] + bias[c]);
        }
    }
}

// ---------------------------------------------------------------------------
// Fallback path (proven 3-kernel pipeline) in case cooperative launch is
// rejected by the runtime / graph capture.
// ---------------------------------------------------------------------------
__global__ __launch_bounds__(256) void transpose_k(const float* __restrict__ x,
                                                   float* __restrict__ xt,
                                                   float4* __restrict__ zero4) {
    {
        int g = blockIdx.x * 256 + threadIdx.x;
        if (g < 32768) zero4[g] = make_float4(0.f, 0.f, 0.f, 0.f);
    }
    __shared__ float tile[32][65];
    const int i0 = blockIdx.x * 64;
    const int t  = threadIdx.x;
    const int w  = t >> 6;
    const int l  = t & 63;
    const bool iok = (i0 + l) < INPUT_DIM;
    #pragma unroll
    for (int bb = 0; bb < 8; ++bb) {
        int b = w * 8 + bb;
        tile[b][l] = iok ? x[b * INPUT_DIM + i0 + l] : 0.f;
    }
    __syncthreads();
    float4* __restrict__ xt4 = (float4*)xt;
    #pragma unroll
    for (int rep = 0; rep < 2; ++rep) {
        int f  = t + rep * 256;
        int il = f >> 3;
        int b4 = f & 7;
        if (i0 + il < INPUT_DIM)
            xt4[(size_t)(i0 + il) * 8 + b4] =
                make_float4(tile[b4 * 4 + 0][il], tile[b4 * 4 + 1][il],
                            tile[b4 * 4 + 2][il], tile[b4 * 4 + 3][il]);
    }
}

__global__ __launch_bounds__(512) void scatter_k(const int* __restrict__ idx,
                                                 const float* __restrict__ kv,
                                                 const float* __restrict__ xt,
                                                 float* __restrict__ ws2,
                                                 float* __restrict__ spill) {
    __shared__ float part[32 * 128];
    __shared__ int   colA[4];

    const int t    = threadIdx.x;
    const int rl   = t & 3;
    const int bg   = (t >> 2) & 3;
    const int es   = t >> 4;
    const int r    = blockIdx.x * 4 + rl;
    const int boff = bg * 8;

    const bool is64 = ((idx[3] | idx[5] | idx[7]) == 0);
    const int  col0 = is64 ? idx[4 * r + 2] : idx[2 * r + 1];

    const int base = r + UNITS * es;
    int   rows[8], cols[8];
    float vals[8];
    if (is64) {
        const int4* __restrict__ p = (const int4*)idx;
        #pragma unroll
        for (int j = 0; j < 8; ++j) {
            int  e  = base + j * 65536;
            bool ok = e < NNZ;
            int4 q  = ok ? p[e] : make_int4(0, 0, col0, 0);
            rows[j] = q.x; cols[j] = q.z;
            vals[j] = ok ? kv[e] : 0.f;
        }
    } else {
        const int2* __restrict__ p = (const int2*)idx;
        #pragma unroll
        for (int j = 0; j < 8; ++j) {
            int  e  = base + j * 65536;
            bool ok = e < NNZ;
            int2 q  = ok ? p[e] : make_int2(0, col0);
            rows[j] = q.x; cols[j] = q.y;
            vals[j] = ok ? kv[e] : 0.f;
        }
    }

    float4 g0[8], g1[8];
    #pragma unroll
    for (int j = 0; j < 8; ++j) {
        const float4* __restrict__ xr = (const float4*)(xt + rows[j] * 32 + boff);
        g0[j] = xr[0];
        g1[j] = xr[1];
    }
    __builtin_amdgcn_sched_barrier(0);

    float acc[8];
    #pragma unroll
    for (int k = 0; k < 8; ++k) acc[k] = 0.f;

    #pragma unroll
    for (int j = 0; j < 8; ++j) {
        float v = vals[j];
        if (cols[j] == col0) {
            acc[0] += v * g0[j].x; acc[1] += v * g0[j].y;
            acc[2] += v * g0[j].z; acc[3] += v * g0[j].w;
            acc[4] += v * g1[j].x; acc[5] += v * g1[j].y;
            acc[6] += v * g1[j].z; acc[7] += v * g1[j].w;
        } else {
            float* __restrict__ sp = spill + cols[j];
            atomicAdd(sp + (boff + 0) * UNITS, v * g0[j].x);
            atomicAdd(sp + (boff + 1) * UNITS, v * g0[j].y);
            atomicAdd(sp + (boff + 2) * UNITS, v * g0[j].z);
            atomicAdd(sp + (boff + 3) * UNITS, v * g0[j].w);
            atomicAdd(sp + (boff + 4) * UNITS, v * g1[j].x);
            atomicAdd(sp + (boff + 5) * UNITS, v * g1[j].y);
            atomicAdd(sp + (boff + 6) * UNITS, v * g1[j].z);
            atomicAdd(sp + (boff + 7) * UNITS, v * g1[j].w);
        }
    }

    #pragma unroll
    for (int bb = 0; bb < 8; ++bb)
        part[es * 128 + (boff + bb) * 4 + rl] = acc[bb];
    if (t < 4) colA[t] = col0;
    __syncthreads();

    if (t < 128) {
        const int rr = t & 3;
        const int b  = t >> 2;
        float s = 0.f;
        #pragma unroll
        for (int e = 0; e < 32; ++e) s += part[e * 128 + b * 4 + rr];
        atomicAdd(&ws2[b * UNITS + colA[rr]], s);
    }
}

__global__ __launch_bounds__(256) void final_k(const float* __restrict__ ws2,
                                               const float* __restrict__ spill,
                                               const float* __restrict__ bias,
                                               float* __restrict__ out) {
    int tid = blockIdx.x * 256 + threadIdx.x;
    int c   = tid & (UNITS - 1);
    out[tid] = tanhf(ws2[tid] + spill[tid] + bias[c]);
}

// ---------------------------------------------------------------------------
extern "C" void kernel_launch(void* const* d_in, const int* in_sizes, int n_in,
                              void* d_out, int out_size, void* d_ws, size_t ws_size,
                              hipStream_t stream) {
    const float* x    = (const float*)d_in[0];
    const float* kv   = (const float*)d_in[1];
    const float* bias = (const float*)d_in[2];
    const int*   idx  = (const int*)d_in[3];
    float*       out  = (float*)d_out;

    // workspace layout: xt [960000 f] | ws2 [65536 f] | spill [65536 f]
    float* xt    = (float*)d_ws;
    float* ws2   = xt + (size_t)INPUT_DIM * BATCH;
    float* spill = ws2 + BATCH * UNITS;

    void* args[] = {(void*)&x, (void*)&kv, (void*)&bias, (void*)&idx,
                    (void*)&out, (void*)&xt, (void*)&ws2, (void*)&spill};
    hipError_t err = hipLaunchCooperativeKernel((const void*)fused_k,
                                                dim3(512), dim3(512),
                                                args, 0, stream);
    if (err != hipSuccess) {
        // fallback: proven 3-kernel pipeline
        transpose_k<<<(INPUT_DIM + 63) / 64, 256, 0, stream>>>(x, xt, (float4*)ws2);
        scatter_k<<<UNITS / 4, 512, 0, stream>>>(idx, kv, xt, ws2, spill);
        final_k<<<(BATCH * UNITS) / 256, 256, 0, stream>>>(ws2, spill, bias, out);
    }
}

// Round 3
// 81.393 us; speedup vs baseline: 2.6358x; 2.6358x over previous
//
#include <hip/hip_runtime.h>
#include <math.h>

// Problem constants (from reference)
#define INPUT_DIM 30000
#define UNITS     2048
#define NNZ       500000
#define BATCH     32

// ---------------------------------------------------------------------------
// R7: revert to the proven 3-kernel pipeline (R6 post-mortem: cg grid.sync
// costs ~50 us/barrier on gfx950 — cooperative fusion is dead). Changes vs
// the 83.5 us baseline:
//  (a) scatter lane mapping bg-fastest: a quad's 4 lanes now read ONE xt
//      row's contiguous 128 B (requests merge 2:1) and issue same-address
//      idx/kv loads (merge 4:1) — ~60 MB less L1/L2 request traffic.
//  (b) final_k fused into scatter (reduce threads own their (b,col) sum ->
//      write tanh directly); correctness for arbitrary indices kept via
//      claim/flag dirty detection + guard_k that early-exits when clean.
// ---------------------------------------------------------------------------

// Kernel 1: transpose x [32][30000] -> xt [30000][32] + zero ws2/spill/claim/flag.
__global__ __launch_bounds__(256) void transpose_k(const float* __restrict__ x,
                                                   float* __restrict__ xt,
                                                   float4* __restrict__ zero4) {
    // zero ws2 (65536 f) + spill (65536 f) + claim (2048 i) + flag: 33281 float4
    {
        int g = blockIdx.x * 256 + threadIdx.x;
        if (g < 33281) zero4[g] = make_float4(0.f, 0.f, 0.f, 0.f);
    }
    __shared__ float tile[32][65];                // +1 pad: conflict-free
    const int i0 = blockIdx.x * 64;
    const int t  = threadIdx.x;
    const int w  = t >> 6;                        // wave 0..3
    const int l  = t & 63;                        // lane
    const bool iok = (i0 + l) < INPUT_DIM;
    #pragma unroll
    for (int bb = 0; bb < 8; ++bb) {              // 8 batch rows per wave
        int b = w * 8 + bb;
        tile[b][l] = iok ? x[b * INPUT_DIM + i0 + l] : 0.f;
    }
    __syncthreads();
    float4* __restrict__ xt4 = (float4*)xt;
    #pragma unroll
    for (int rep = 0; rep < 2; ++rep) {
        int f  = t + rep * 256;                   // 0..511 float4 slots
        int il = f >> 3;                          // local i 0..63
        int b4 = f & 7;                           // batch quad 0..7
        if (i0 + il < INPUT_DIM)
            xt4[(size_t)(i0 + il) * 8 + b4] =
                make_float4(tile[b4 * 4 + 0][il], tile[b4 * 4 + 1][il],
                            tile[b4 * 4 + 2][il], tile[b4 * 4 + 3][il]);
    }
}

// ---------------------------------------------------------------------------
// Kernel 2: residue-sliced scatter, register accumulation, fused epilogue.
// Thread = (bg 0..3 FASTEST, rl 0..3, es 0..31); grid 512 x 512.
// Entries n = r + 2048*m share column col0(r) for this data; spill path +
// claim collision detection keep arbitrary-index correctness (flag -> guard).
// ---------------------------------------------------------------------------
__global__ __launch_bounds__(512) void scatter_k(const int* __restrict__ idx,
                                                 const float* __restrict__ kv,
                                                 const float* __restrict__ xt,
                                                 float* __restrict__ ws2,
                                                 float* __restrict__ spill,
                                                 const float* __restrict__ bias,
                                                 float* __restrict__ out,
                                                 int* __restrict__ claim,
                                                 int* __restrict__ flag) {
    __shared__ float part[32 * 128];              // [es][b 0..31][rl 0..3]
    __shared__ int   colA[4];

    const int t    = threadIdx.x;
    const int bg   = t & 3;                       // quad shares one entry
    const int rl   = (t >> 2) & 3;
    const int es   = t >> 4;                      // 0..31
    const int r    = blockIdx.x * 4 + rl;         // residue 0..2047
    const int boff = bg * 8;

    // int64 vs int32 index detection (uniform): int64 LE -> high words zero.
    const bool is64 = ((idx[3] | idx[5] | idx[7]) == 0);
    const int  col0 = is64 ? idx[4 * r + 2] : idx[2 * r + 1];

    // early claim: detect col0 collisions across residues (issue now, check
    // the returned value at the end so no wave stalls here)
    int claimOld = 0;
    if ((t & 3) == 0 && t < 16) {                 // t = 0,4,8,12 -> rl = 0..3
        colA[rl] = col0;
        claimOld = atomicAdd(&claim[col0], 1);
    }

    // ---- all 8 idx/kv loads issued together (quad lanes same addr: merge) --
    const int base = r + UNITS * es;              // 0..65535
    int   rows[8], cols[8];
    float vals[8];
    if (is64) {
        const int4* __restrict__ p = (const int4*)idx;
        #pragma unroll
        for (int j = 0; j < 8; ++j) {
            int  e  = base + j * 65536;           // entry stripe
            bool ok = e < NNZ;
            int4 q  = ok ? p[e] : make_int4(0, 0, col0, 0);
            rows[j] = q.x; cols[j] = q.z;
            vals[j] = ok ? kv[e] : 0.f;
        }
    } else {
        const int2* __restrict__ p = (const int2*)idx;
        #pragma unroll
        for (int j = 0; j < 8; ++j) {
            int  e  = base + j * 65536;
            bool ok = e < NNZ;
            int2 q  = ok ? p[e] : make_int2(0, col0);
            rows[j] = q.x; cols[j] = q.y;
            vals[j] = ok ? kv[e] : 0.f;
        }
    }

    // ---- 16 gathers in flight; quad covers one row's 128 B contiguously ----
    float4 g0[8], g1[8];
    #pragma unroll
    for (int j = 0; j < 8; ++j) {
        const float4* __restrict__ xr = (const float4*)(xt + rows[j] * 32 + boff);
        g0[j] = xr[0];
        g1[j] = xr[1];
    }
    __builtin_amdgcn_sched_barrier(0);            // keep gathers issued first

    float acc[8];
    #pragma unroll
    for (int k = 0; k < 8; ++k) acc[k] = 0.f;

    #pragma unroll
    for (int j = 0; j < 8; ++j) {
        float v = vals[j];
        if (cols[j] == col0) {                    // uniformly true for this data
            acc[0] += v * g0[j].x; acc[1] += v * g0[j].y;
            acc[2] += v * g0[j].z; acc[3] += v * g0[j].w;
            acc[4] += v * g1[j].x; acc[5] += v * g1[j].y;
            acc[6] += v * g1[j].z; acc[7] += v * g1[j].w;
        } else {                                  // correctness fallback
            atomicAdd(flag, 1);                   // force guard recompute
            float* __restrict__ sp = spill + cols[j];
            atomicAdd(sp + (boff + 0) * UNITS, v * g0[j].x);
            atomicAdd(sp + (boff + 1) * UNITS, v * g0[j].y);
            atomicAdd(sp + (boff + 2) * UNITS, v * g0[j].z);
            atomicAdd(sp + (boff + 3) * UNITS, v * g0[j].w);
            atomicAdd(sp + (boff + 4) * UNITS, v * g1[j].x);
            atomicAdd(sp + (boff + 5) * UNITS, v * g1[j].y);
            atomicAdd(sp + (boff + 6) * UNITS, v * g1[j].z);
            atomicAdd(sp + (boff + 7) * UNITS, v * g1[j].w);
        }
    }

    // combine 32 es-stripes via LDS (one-time; conflicts cheap)
    #pragma unroll
    for (int bb = 0; bb < 8; ++bb)
        part[es * 128 + (boff + bb) * 4 + rl] = acc[bb];
    if (claimOld != 0) atomicAdd(flag, 1);        // deferred collision check
    __syncthreads();

    if (t < 128) {
        const int rr = t & 3;
        const int b  = t >> 2;                    // 0..31
        float s = 0.f;
        #pragma unroll
        for (int e = 0; e < 32; ++e) s += part[e * 128 + b * 4 + rr];
        const int c = colA[rr];
        // ws2 keeps the full sum for the guard path (collisions accumulate)
        atomicAdd(&ws2[b * UNITS + c], s);
        // fused epilogue: valid whenever no spill and no collision anywhere
        out[b * UNITS + c] = tanhf(s + bias[c]);
    }
}

// ---------------------------------------------------------------------------
// Kernel 3: guard — early-exits on one scalar read when the fused epilogue
// was valid (flag == 0); otherwise recomputes out = tanh(ws2 + spill + bias).
// ---------------------------------------------------------------------------
__global__ __launch_bounds__(256) void guard_k(const float* __restrict__ ws2,
                                               const float* __restrict__ spill,
                                               const float* __restrict__ bias,
                                               const int* __restrict__ flag,
                                               float* __restrict__ out) {
    if (__builtin_expect(*flag == 0, 1)) return;  // clean: launch-cost only
    int tid = blockIdx.x * 256 + threadIdx.x;     // 0..65535
    int c   = tid & (UNITS - 1);
    out[tid] = tanhf(ws2[tid] + spill[tid] + bias[c]);
}

// ---------------------------------------------------------------------------
extern "C" void kernel_launch(void* const* d_in, const int* in_sizes, int n_in,
                              void* d_out, int out_size, void* d_ws, size_t ws_size,
                              hipStream_t stream) {
    const float* x    = (const float*)d_in[0];
    const float* kv   = (const float*)d_in[1];
    const float* bias = (const float*)d_in[2];
    const int*   idx  = (const int*)d_in[3];
    float*       out  = (float*)d_out;

    // workspace: xt [960000 f] | ws2 [65536 f] | spill [65536 f] | claim [2048 i] | flag [1 i]
    float* xt    = (float*)d_ws;
    float* ws2   = xt + (size_t)INPUT_DIM * BATCH;
    float* spill = ws2 + BATCH * UNITS;
    int*   claim = (int*)(spill + BATCH * UNITS);
    int*   flag  = claim + UNITS;

    transpose_k<<<(INPUT_DIM + 63) / 64, 256, 0, stream>>>(x, xt, (float4*)ws2);
    scatter_k<<<UNITS / 4, 512, 0, stream>>>(idx, kv, xt, ws2, spill, bias, out,
                                             claim, flag);
    guard_k<<<(BATCH * UNITS) / 256, 256, 0, stream>>>(ws2, spill, bias, flag, out);
}

// Round 4
// 78.468 us; speedup vs baseline: 2.7340x; 1.0373x over previous
//
#include <hip/hip_runtime.h>
#include <math.h>

// Problem constants (from reference)
#define INPUT_DIM 30000
#define UNITS     2048
#define NNZ       500000
#define BATCH     32

// ---------------------------------------------------------------------------
// R8: occupancy-first restructure (R7 post-mortem: in-kernel changes DO move
// dur_us; both kernels were running at <=50% wave capacity in a cold-miss
// latency-bound regime).
//  - scatter: 1 residue/WG, grid 2048x512, octet mapping (8 lanes x 16B =
//    one 128B xt row). Per-thread state ~40 VGPR -> launch_bounds(512,8)
//    holds 64 VGPR / 32 waves per CU (2x concurrency vs R7).
//  - XCD-chunk swizzle r=(bid&7)*256+(bid>>3): consecutive residues (which
//    share idx/kv cache lines) land on the same XCD's L2 -> no fetch
//    amplification from the 1-residue/WG split.
//  - transpose: 32-col tiles, 938 WGs (~15 waves/CU, was ~7).
// Correctness for arbitrary indices kept: spill path + claim collision
// detection + guard kernel (early-exit when clean).
// ---------------------------------------------------------------------------

// Kernel 1: transpose x [32][30000] -> xt [30000][32] + zero ws2/spill/claim/flag.
__global__ __launch_bounds__(256) void transpose_k(const float* __restrict__ x,
                                                   float* __restrict__ xt,
                                                   float4* __restrict__ zero4) {
    // zero ws2 (65536 f) + spill (65536 f) + claim (2048 i) + flag: 33281 float4
    {
        int g = blockIdx.x * 256 + threadIdx.x;
        if (g < 33281) zero4[g] = make_float4(0.f, 0.f, 0.f, 0.f);
    }
    __shared__ float tile[32][33];                // +1 pad
    const int i0 = blockIdx.x * 32;
    const int t  = threadIdx.x;
    const int l  = t & 31;                        // col within tile
    #pragma unroll
    for (int rep = 0; rep < 4; ++rep) {           // 4 batch rows per thread
        int b = rep * 8 + (t >> 5);
        if (i0 + l < INPUT_DIM)
            tile[b][l] = x[b * INPUT_DIM + i0 + l];
        else
            tile[b][l] = 0.f;
    }
    __syncthreads();
    const int il = t >> 3;                        // 0..31
    const int b4 = t & 7;                         // batch quad 0..7
    if (i0 + il < INPUT_DIM)
        ((float4*)xt)[(size_t)(i0 + il) * 8 + b4] =
            make_float4(tile[b4 * 4 + 0][il], tile[b4 * 4 + 1][il],
                        tile[b4 * 4 + 2][il], tile[b4 * 4 + 3][il]);
}

// ---------------------------------------------------------------------------
// Kernel 2: residue-per-WG scatter, register accumulation, fused epilogue.
// Thread = (bg 0..7 fastest, es 0..63); 4 entries/thread (m = es + 64*j).
// Grid 2048 x 512; launch_bounds(512,8) -> 64 VGPR cap, 32 waves/CU.
// ---------------------------------------------------------------------------
__global__ __launch_bounds__(512, 8) void scatter_k(const int* __restrict__ idx,
                                                    const float* __restrict__ kv,
                                                    const float* __restrict__ xt,
                                                    float* __restrict__ ws2,
                                                    float* __restrict__ spill,
                                                    const float* __restrict__ bias,
                                                    float* __restrict__ out,
                                                    int* __restrict__ claim,
                                                    int* __restrict__ flag) {
    __shared__ float part[64 * 32];               // [es][b]  8 KB

    const int t    = threadIdx.x;
    const int bg   = t & 7;                       // octet covers one 128B row
    const int es   = t >> 3;                      // 0..63
    // XCD-chunk swizzle: XCD (bid&7) owns residues [ (bid&7)*256, +256 ) so
    // consecutive residues (same idx/kv cache lines) share one L2.
    const int r    = ((blockIdx.x & 7) << 8) + (blockIdx.x >> 3);  // 0..2047
    const int boff = bg * 4;

    // int64 vs int32 index detection (uniform): int64 LE -> high words zero.
    const bool is64 = ((idx[3] | idx[5] | idx[7]) == 0);
    const int  col0 = is64 ? idx[4 * r + 2] : idx[2 * r + 1];  // WG-uniform

    // claim: detect col0 collisions across residues (check deferred to end)
    int claimOld = 0;
    if (t == 0) claimOld = atomicAdd(&claim[col0], 1);

    // ---- all 4 idx/kv loads issued together (octet lanes same addr) ----
    const int base = r + UNITS * es;              // m = es + 64*j stripes
    int   rows[4], cols[4];
    float vals[4];
    if (is64) {
        const int4* __restrict__ p = (const int4*)idx;
        #pragma unroll
        for (int j = 0; j < 4; ++j) {
            int  e  = base + j * (UNITS * 64);    // +131072 entries
            bool ok = e < NNZ;
            int4 q  = ok ? p[e] : make_int4(0, 0, col0, 0);
            rows[j] = q.x; cols[j] = q.z;
            vals[j] = ok ? kv[e] : 0.f;
        }
    } else {
        const int2* __restrict__ p = (const int2*)idx;
        #pragma unroll
        for (int j = 0; j < 4; ++j) {
            int  e  = base + j * (UNITS * 64);
            bool ok = e < NNZ;
            int2 q  = ok ? p[e] : make_int2(0, col0);
            rows[j] = q.x; cols[j] = q.y;
            vals[j] = ok ? kv[e] : 0.f;
        }
    }

    // ---- 4 gathers in flight (16B/lane; octet jointly covers 128B row) ----
    float4 g[4];
    #pragma unroll
    for (int j = 0; j < 4; ++j)
        g[j] = *(const float4*)(xt + rows[j] * 32 + boff);
    __builtin_amdgcn_sched_barrier(0);            // keep gathers issued first

    float acc[4] = {0.f, 0.f, 0.f, 0.f};
    #pragma unroll
    for (int j = 0; j < 4; ++j) {
        float v = vals[j];
        if (cols[j] == col0) {                    // uniformly true for this data
            acc[0] += v * g[j].x; acc[1] += v * g[j].y;
            acc[2] += v * g[j].z; acc[3] += v * g[j].w;
        } else {                                  // correctness fallback
            atomicAdd(flag, 1);
            float* __restrict__ sp = spill + cols[j];
            atomicAdd(sp + (boff + 0) * UNITS, v * g[j].x);
            atomicAdd(sp + (boff + 1) * UNITS, v * g[j].y);
            atomicAdd(sp + (boff + 2) * UNITS, v * g[j].z);
            atomicAdd(sp + (boff + 3) * UNITS, v * g[j].w);
        }
    }

    // combine 64 es-stripes via LDS
    #pragma unroll
    for (int bb = 0; bb < 4; ++bb)
        part[es * 32 + boff + bb] = acc[bb];
    if (claimOld != 0) atomicAdd(flag, 1);        // deferred collision check
    __syncthreads();

    if (t < 32) {
        const int b = t;                          // batch row
        float s = 0.f;
        #pragma unroll
        for (int e = 0; e < 64; ++e) s += part[e * 32 + b];
        // ws2 keeps the full sum for the guard path (collisions accumulate)
        atomicAdd(&ws2[b * UNITS + col0], s);
        // fused epilogue: valid whenever no spill and no collision anywhere
        out[b * UNITS + col0] = tanhf(s + bias[col0]);
    }
}

// ---------------------------------------------------------------------------
// Kernel 3: guard — early-exits on one scalar read when the fused epilogue
// was valid (flag == 0); otherwise recomputes out = tanh(ws2 + spill + bias).
// ---------------------------------------------------------------------------
__global__ __launch_bounds__(256) void guard_k(const float* __restrict__ ws2,
                                               const float* __restrict__ spill,
                                               const float* __restrict__ bias,
                                               const int* __restrict__ flag,
                                               float* __restrict__ out) {
    if (__builtin_expect(*flag == 0, 1)) return;  // clean: launch-cost only
    int tid = blockIdx.x * 256 + threadIdx.x;     // 0..65535
    int c   = tid & (UNITS - 1);
    out[tid] = tanhf(ws2[tid] + spill[tid] + bias[c]);
}

// ---------------------------------------------------------------------------
extern "C" void kernel_launch(void* const* d_in, const int* in_sizes, int n_in,
                              void* d_out, int out_size, void* d_ws, size_t ws_size,
                              hipStream_t stream) {
    const float* x    = (const float*)d_in[0];
    const float* kv   = (const float*)d_in[1];
    const float* bias = (const float*)d_in[2];
    const int*   idx  = (const int*)d_in[3];
    float*       out  = (float*)d_out;

    // workspace: xt [960000 f] | ws2 [65536 f] | spill [65536 f] | claim [2048 i] | flag [1 i]
    float* xt    = (float*)d_ws;
    float* ws2   = xt + (size_t)INPUT_DIM * BATCH;
    float* spill = ws2 + BATCH * UNITS;
    int*   claim = (int*)(spill + BATCH * UNITS);
    int*   flag  = claim + UNITS;

    transpose_k<<<(INPUT_DIM + 31) / 32, 256, 0, stream>>>(x, xt, (float4*)ws2);
    scatter_k<<<UNITS, 512, 0, stream>>>(idx, kv, xt, ws2, spill, bias, out,
                                         claim, flag);
    guard_k<<<(BATCH * UNITS) / 256, 256, 0, stream>>>(ws2, spill, bias, flag, out);
}